// Round 11
// baseline (500.602 us; speedup 1.0000x reference)
//
#include <hip/hip_runtime.h>
#include <hip/hip_bf16.h>
#include <math.h>

// dims
#define Bb 2
#define Nn 2048
#define Cc 256
#define Kk 64
#define Hh 4
#define DHh 32
#define DMm 128
#define DIi 16
#define Ll 3
#define Ss 64
#define OUTn 10

__device__ __forceinline__ float gelu_exact(float x) {
    return 0.5f * x * (1.0f + erff(x * 0.70710678118654752f));
}

// 128-dot with 4 interleaved accumulator chains
__device__ __forceinline__ float dot128_4(const float* a, const float* __restrict__ w) {
    float s0 = 0.f, s1 = 0.f, s2 = 0.f, s3 = 0.f;
#pragma unroll
    for (int e = 0; e < 128; e += 4) {
        s0 = fmaf(a[e],     w[e],     s0);
        s1 = fmaf(a[e + 1], w[e + 1], s1);
        s2 = fmaf(a[e + 2], w[e + 2], s2);
        s3 = fmaf(a[e + 3], w[e + 3], s3);
    }
    return (s0 + s1) + (s2 + s3);
}

// ---------------- K1: top-k (full bitonic sort of 2048, descending, tie -> lower idx) --------
__global__ __launch_bounds__(1024) void k_topk(const float* __restrict__ x,
                                               float* __restrict__ vals,
                                               float* __restrict__ mz) {
    __shared__ float key[Nn];
    __shared__ int   idx[Nn];
    const int b = blockIdx.x, t = threadIdx.x;
    for (int i = t; i < Nn; i += 1024) { key[i] = x[b * Nn + i]; idx[i] = i; }
    __syncthreads();
    for (int k = 2; k <= Nn; k <<= 1) {
        for (int j = k >> 1; j > 0; j >>= 1) {
            for (int i = t; i < Nn; i += 1024) {
                int ixj = i ^ j;
                if (ixj > i) {
                    float va = key[i], vb = key[ixj];
                    int ia = idx[i], ib = idx[ixj];
                    bool aG = (va > vb) || (va == vb && ia < ib);
                    bool desc = ((i & k) == 0);
                    bool dosw = desc ? (!aG) : aG;
                    if (dosw) { key[i] = vb; key[ixj] = va; idx[i] = ib; idx[ixj] = ia; }
                }
            }
            __syncthreads();
        }
    }
    if (t < Cc) {
        vals[b * Cc + t] = log1pf(fmaxf(key[t], 0.f));
        mz[b * Cc + t] = (float)idx[t];
    }
}

// ---------------- K2: binding encoder fused with layer-0 QKV ----------------
__global__ __launch_bounds__(256) void k_enc_qkv(const float* __restrict__ vals,
                                                 const float* __restrict__ mz,
                                                 const float* __restrict__ emb_roles,
                                                 const float* __restrict__ filler_w,
                                                 const float* __restrict__ conv_w,
                                                 const float* __restrict__ conv_b,
                                                 const float* __restrict__ outer_w,
                                                 const float* __restrict__ g,
                                                 const float* __restrict__ bb,
                                                 float* __restrict__ bnd,
                                                 const float* __restrict__ qw, const float* __restrict__ qb,
                                                 const float* __restrict__ kw, const float* __restrict__ kb,
                                                 const float* __restrict__ vw, const float* __restrict__ vb,
                                                 const float* __restrict__ w1,
                                                 float* __restrict__ q, float* __restrict__ k,
                                                 float* __restrict__ v, float* __restrict__ qp,
                                                 float* __restrict__ kp) {
    __shared__ float roles[DIi], fill[DIi], outerv[256], ps[2][128];
    __shared__ float redA[4], redB[4];
    __shared__ float bndrow[DMm], qrow[DMm], krow[DMm];
    const int bc = blockIdx.x;
    const int b = bc >> 8, c = bc & 255;
    const int t = threadIdx.x;
    const float NEG = -1.3157629102823120f; // -ln(10000)/7
    if (t < DIi) {
        float mzv = mz[bc];
        float rr;
        if (t < 8) rr = sinf(mzv * expf((float)t * NEG));
        else       rr = cosf(mzv * expf((float)(t - 8) * NEG));
        roles[t] = rr + emb_roles[c * DIi + t];
    } else if (t < 2 * DIi) {
        int e = t - DIi;
        float vc = vals[bc];
        float fp = vc * filler_w[e];
        float acc = conv_b[e];
#pragma unroll
        for (int kk = 0; kk < 5; ++kk) {
            int pos = c - 2 + kk;
            pos = pos < 0 ? -pos : (pos >= Cc ? 2 * Cc - 2 - pos : pos);
            acc = fmaf(vals[b * Cc + pos], conv_w[e * 5 + kk], acc);
        }
        fill[e] = gelu_exact(fp + gelu_exact(acc));
    }
    __syncthreads();
    outerv[t] = roles[t >> 4] * fill[t & 15];
    __syncthreads();
    const int o = t & 127, seg = t >> 7;
    float acc = dot128_4(outerv + seg * 128, outer_w + o * 256 + seg * 128);
    ps[seg][o] = acc;
    __syncthreads();
    float t1 = 0.f;
    if (t < 128) t1 = ps[0][t] + ps[1][t];
    float sa = (t < 128) ? t1 : 0.f, sb = (t < 128) ? t1 * t1 : 0.f;
#pragma unroll
    for (int off = 1; off < 64; off <<= 1) { sa += __shfl_xor(sa, off); sb += __shfl_xor(sb, off); }
    if ((t & 63) == 0) { redA[t >> 6] = sa; redB[t >> 6] = sb; }
    __syncthreads();
    float S = (redA[0] + redA[1]) + (redA[2] + redA[3]);
    float Q = (redB[0] + redB[1]) + (redB[2] + redB[3]);
    float mean = S * (1.f / 128.f);
    float var = Q * (1.f / 128.f) - mean * mean;
    if (t < 128) {
        float nv = (t1 - mean) / sqrtf(var + 1e-5f) * g[t] + bb[t];
        bnd[bc * DMm + t] = nv;
        bndrow[t] = nv;
    }
    __syncthreads();
    {   // pass A: q (t<128) and k (t>=128)
        const float* W  = (t < 128) ? qw : kw;
        const float* Bi = (t < 128) ? qb : kb;
        float val = Bi[o] + dot128_4(bndrow, W + o * DMm);
        const int h = o >> 5, dd = o & 31;
        const int gi = ((b * Hh + h) * Cc + c) * DHh + dd;
        if (t < 128) { q[gi] = val; qrow[o] = val; }
        else         { k[gi] = val; krow[o] = val; }
    }
    __syncthreads();
    if (t < 128) {   // pass B1: v
        float val = vb[t] + dot128_4(bndrow, vw + t * DMm);
        const int h = t >> 5, dd = t & 31;
        v[((b * Hh + h) * Cc + c) * DHh + dd] = val;
    } else {         // pass B2: qp/kp
        const int tt = t - 128, h = tt >> 5, dd = tt & 31;
        const float* wrq = w1 + dd * 96;
        float aq = 0.f, ak = 0.f;
#pragma unroll
        for (int e = 0; e < DHh; ++e) {
            aq = fmaf(qrow[h * 32 + e], wrq[e],      aq);
            ak = fmaf(krow[h * 32 + e], wrq[32 + e], ak);
        }
        const int gi = ((b * Hh + h) * Cc + c) * DHh + dd;
        qp[gi] = aq; kp[gi] = ak;
    }
}

// ---------------- K4: 2-heads-per-block attention ----------------
__global__ __launch_bounds__(256) void k_attn(const float* __restrict__ q,
                                              const float* __restrict__ k,
                                              const float* __restrict__ v,
                                              const float* __restrict__ qp,
                                              const float* __restrict__ kp,
                                              const float* __restrict__ w1,
                                              const float* __restrict__ rb1,
                                              const float* __restrict__ w2,
                                              const float* __restrict__ rb2,
                                              float* __restrict__ aout) {
    __shared__ float w3s[DHh * DHh];
    __shared__ float qs[2][DHh], qbase[2][DHh], w2s[DHh];
    __shared__ float scL[2][Cc], aw[2][Cc];
    __shared__ float4 pr4[2][8][16];
    const int bid = blockIdx.x;          // b*512 + hp*256 + i
    const int t = threadIdx.x;           // 0..255
    const int lane = t & 63, wave = t >> 6;
    const int i = bid & 255, hp = (bid >> 8) & 1, b = bid >> 9;
    const int bh0 = (b * Hh + 2 * hp), bh1 = bh0 + 1;
    const int rb0 = (bh0 * Cc + i) * DHh, rb1o = (bh1 * Cc + i) * DHh;

    {   // stage w3 (1024 floats): one float4 per thread
        int row = t >> 3, c4 = t & 7;
        float4 vv = *reinterpret_cast<const float4*>(w1 + row * 96 + 64 + c4 * 4);
        *reinterpret_cast<float4*>(&w3s[row * 32 + c4 * 4]) = vv;
    }
    if (t < 32) {
        qs[0][t] = q[rb0 + t];
        qs[1][t] = q[rb1o + t];
        float rb = rb1[t];
        qbase[0][t] = qp[rb0 + t] + rb;
        qbase[1][t] = qp[rb1o + t] + rb;
        w2s[t] = w2[t];
    }
    __syncthreads();
    const float rb2v = rb2[0];

    // --- scores for column j = t, both heads ---
    float p0[32], p1[32], base0[32], base1[32];
    {
        const int jb0 = (bh0 * Cc + t) * DHh;
        const float4* k4  = reinterpret_cast<const float4*>(k + jb0);
        const float4* kp4 = reinterpret_cast<const float4*>(kp + jb0);
#pragma unroll
        for (int m = 0; m < 8; ++m) {
            float4 a = k4[m];
            p0[4*m]   = qs[0][4*m]   * a.x;
            p0[4*m+1] = qs[0][4*m+1] * a.y;
            p0[4*m+2] = qs[0][4*m+2] * a.z;
            p0[4*m+3] = qs[0][4*m+3] * a.w;
            float4 bq = kp4[m];
            base0[4*m]   = qbase[0][4*m]   + bq.x;
            base0[4*m+1] = qbase[0][4*m+1] + bq.y;
            base0[4*m+2] = qbase[0][4*m+2] + bq.z;
            base0[4*m+3] = qbase[0][4*m+3] + bq.w;
        }
        const int jb1 = (bh1 * Cc + t) * DHh;
        const float4* k4b  = reinterpret_cast<const float4*>(k + jb1);
        const float4* kp4b = reinterpret_cast<const float4*>(kp + jb1);
#pragma unroll
        for (int m = 0; m < 8; ++m) {
            float4 a = k4b[m];
            p1[4*m]   = qs[1][4*m]   * a.x;
            p1[4*m+1] = qs[1][4*m+1] * a.y;
            p1[4*m+2] = qs[1][4*m+2] * a.z;
            p1[4*m+3] = qs[1][4*m+3] * a.w;
            float4 bq = kp4b[m];
            base1[4*m]   = qbase[1][4*m]   + bq.x;
            base1[4*m+1] = qbase[1][4*m+1] + bq.y;
            base1[4*m+2] = qbase[1][4*m+2] + bq.z;
            base1[4*m+3] = qbase[1][4*m+3] + bq.w;
        }
    }
    float acc0 = 0.f, acc1 = 0.f;
#pragma unroll 4
    for (int d = 0; d < 32; ++d) {
        const float4* w4 = reinterpret_cast<const float4*>(&w3s[d * 32]);
        float r0 = base0[d], r1 = base1[d];
#pragma unroll
        for (int m = 0; m < 8; ++m) {
            float4 w = w4[m];
            r0 = fmaf(p0[4*m],   w.x, r0); r1 = fmaf(p1[4*m],   w.x, r1);
            r0 = fmaf(p0[4*m+1], w.y, r0); r1 = fmaf(p1[4*m+1], w.y, r1);
            r0 = fmaf(p0[4*m+2], w.z, r0); r1 = fmaf(p1[4*m+2], w.z, r1);
            r0 = fmaf(p0[4*m+3], w.w, r0); r1 = fmaf(p1[4*m+3], w.w, r1);
        }
        float wv = w2s[d];
        acc0 = fmaf(gelu_exact(r0), wv, acc0);
        acc1 = fmaf(gelu_exact(r1), wv, acc1);
    }
    scL[0][t] = (acc0 + rb2v) * 0.17677669529663689f;
    scL[1][t] = (acc1 + rb2v) * 0.17677669529663689f;
    __syncthreads();

    // --- waves 0,1 each sort one head's 256 scores and write softmax weights ---
    if (wave < 2) {
        const float* sl = scL[wave];
        float v0 = sl[lane], v1 = sl[64 + lane], v2 = sl[128 + lane], v3 = sl[192 + lane];
        auto cx_lane = [&](int k_, int j_) {
            float o0 = __shfl_xor(v0, j_), o1 = __shfl_xor(v1, j_);
            float o2 = __shfl_xor(v2, j_), o3 = __shfl_xor(v3, j_);
            bool lower = ((lane & j_) == 0);
            bool d0 = (((0 * 64 + lane) & k_) == 0);
            bool d1 = (((1 * 64 + lane) & k_) == 0);
            bool d2 = (((2 * 64 + lane) & k_) == 0);
            bool d3 = (((3 * 64 + lane) & k_) == 0);
            v0 = (lower == d0) ? fmaxf(v0, o0) : fminf(v0, o0);
            v1 = (lower == d1) ? fmaxf(v1, o1) : fminf(v1, o1);
            v2 = (lower == d2) ? fmaxf(v2, o2) : fminf(v2, o2);
            v3 = (lower == d3) ? fmaxf(v3, o3) : fminf(v3, o3);
        };
        auto cx_reg1 = [&](int k_) {
            bool dA = (((0 * 64) & k_) == 0);
            bool dB = (((2 * 64) & k_) == 0);
            float aA = v0, bA = v1;
            v0 = dA ? fmaxf(aA, bA) : fminf(aA, bA);
            v1 = dA ? fminf(aA, bA) : fmaxf(aA, bA);
            float aB = v2, bB = v3;
            v2 = dB ? fmaxf(aB, bB) : fminf(aB, bB);
            v3 = dB ? fminf(aB, bB) : fmaxf(aB, bB);
        };
        auto cx_reg2 = [&](int k_) {
            bool dA = (((0 * 64) & k_) == 0);
            bool dB = (((1 * 64) & k_) == 0);
            float aA = v0, bA = v2;
            v0 = dA ? fmaxf(aA, bA) : fminf(aA, bA);
            v2 = dA ? fminf(aA, bA) : fmaxf(aA, bA);
            float aB = v1, bB = v3;
            v1 = dB ? fmaxf(aB, bB) : fminf(aB, bB);
            v3 = dB ? fminf(aB, bB) : fmaxf(aB, bB);
        };
        cx_lane(2, 1);
        cx_lane(4, 2); cx_lane(4, 1);
        cx_lane(8, 4); cx_lane(8, 2); cx_lane(8, 1);
        cx_lane(16, 8); cx_lane(16, 4); cx_lane(16, 2); cx_lane(16, 1);
        cx_lane(32, 16); cx_lane(32, 8); cx_lane(32, 4); cx_lane(32, 2); cx_lane(32, 1);
        cx_lane(64, 32); cx_lane(64, 16); cx_lane(64, 8); cx_lane(64, 4); cx_lane(64, 2); cx_lane(64, 1);
        cx_reg1(128);
        cx_lane(128, 32); cx_lane(128, 16); cx_lane(128, 8); cx_lane(128, 4); cx_lane(128, 2); cx_lane(128, 1);
        cx_reg2(256); cx_reg1(256);
        cx_lane(256, 32); cx_lane(256, 16); cx_lane(256, 8); cx_lane(256, 4); cx_lane(256, 2); cx_lane(256, 1);

        const float minv = __shfl(v0, 63);
        const float mx   = __shfl(v0, 0);
        float ls = 0.f;
        ls += expf(v0 - mx);
        ls += (v1 >= minv) ? expf(v1 - mx) : 0.f;
        ls += (v2 >= minv) ? expf(v2 - mx) : 0.f;
        ls += (v3 >= minv) ? expf(v3 - mx) : 0.f;
#pragma unroll
        for (int off = 1; off < 64; off <<= 1) ls += __shfl_xor(ls, off);
        const float inv = 1.f / ls;
#pragma unroll
        for (int r = 0; r < 4; ++r) {
            int c = r * 64 + lane;
            float s = sl[c];
            aw[wave][c] = (s >= minv) ? expf(s - mx) * inv : 0.f;
        }
    }
    __syncthreads();

    // --- attn @ v: thread = (h = t>>7, jg = (t>>3)&15, dq = t&7), 16 j's each ---
    {
        const int h = t >> 7, jg = (t >> 3) & 15, dq = t & 7;
        const int bh = bh0 + h;
        const float4* v4 = reinterpret_cast<const float4*>(v) + (size_t)(bh * Cc) * 8 + dq;
        float4 a4; a4.x = 0.f; a4.y = 0.f; a4.z = 0.f; a4.w = 0.f;
#pragma unroll
        for (int jj = 0; jj < 16; ++jj) {
            int j = jg * 16 + jj;
            float a = aw[h][j];
            float4 vv = v4[j * 8];
            a4.x = fmaf(a, vv.x, a4.x);
            a4.y = fmaf(a, vv.y, a4.y);
            a4.z = fmaf(a, vv.z, a4.z);
            a4.w = fmaf(a, vv.w, a4.w);
        }
        pr4[h][dq][jg] = a4;
    }
    __syncthreads();
    if (t < 16) {
        const int h = t >> 3, dq = t & 7;
        float4 s; s.x = 0.f; s.y = 0.f; s.z = 0.f; s.w = 0.f;
#pragma unroll
        for (int jg = 0; jg < 16; ++jg) {
            float4 p = pr4[h][dq][jg];
            s.x += p.x; s.y += p.y; s.z += p.z; s.w += p.w;
        }
        float* dst = aout + (b * Cc + i) * DMm + (2 * hp + h) * DHh + dq * 4;
        *reinterpret_cast<float4*>(dst) = s;
    }
}

// ---------------- K5: o-proj + LN + FFN + LN fused with next-layer QKV ----------------
__global__ __launch_bounds__(512) void k_ffn_qkv(const float* __restrict__ aout,
                                                 const float* __restrict__ ow, const float* __restrict__ ob,
                                                 const float* __restrict__ n1g, const float* __restrict__ n1b,
                                                 const float* __restrict__ fw1, const float* __restrict__ fb1,
                                                 const float* __restrict__ fw2, const float* __restrict__ fb2,
                                                 const float* __restrict__ n2g, const float* __restrict__ n2b,
                                                 float* __restrict__ bnd,
                                                 int do_qkv,
                                                 const float* __restrict__ qw, const float* __restrict__ qb,
                                                 const float* __restrict__ kw, const float* __restrict__ kb,
                                                 const float* __restrict__ vw, const float* __restrict__ vb,
                                                 const float* __restrict__ w1,
                                                 float* __restrict__ q, float* __restrict__ k,
                                                 float* __restrict__ v, float* __restrict__ qp,
                                                 float* __restrict__ kp) {
    __shared__ float arow[DMm], b1row[DMm], ff1[512], ps[4][128];
    __shared__ float redA[8], redB[8], redC[8], redD[8];
    __shared__ float bndrow[DMm], qrow[DMm], krow[DMm];
    const int bc = blockIdx.x, t = threadIdx.x;
    const int b = bc >> 8, c = bc & 255;
    if (t < 128) arow[t] = aout[bc * DMm + t];
    __syncthreads();
    const int o = t & 127, seg = t >> 7;
    {
        const float* wr = ow + o * DMm + seg * 32;
        const float* ar = arow + seg * 32;
        float pa = 0.f;
#pragma unroll
        for (int e = 0; e < 32; ++e) pa = fmaf(ar[e], wr[e], pa);
        ps[seg][o] = pa;
    }
    __syncthreads();
    float t1 = 0.f;
    if (t < 128) t1 = bnd[bc * DMm + t] + ob[t] + ((ps[0][t] + ps[1][t]) + (ps[2][t] + ps[3][t]));
    float sa = (t < 128) ? t1 : 0.f, sb = (t < 128) ? t1 * t1 : 0.f;
#pragma unroll
    for (int off = 1; off < 64; off <<= 1) { sa += __shfl_xor(sa, off); sb += __shfl_xor(sb, off); }
    if ((t & 63) == 0) { redA[t >> 6] = sa; redB[t >> 6] = sb; }
    __syncthreads();
    float S = 0.f, Q = 0.f;
#pragma unroll
    for (int r = 0; r < 8; ++r) { S += redA[r]; Q += redB[r]; }
    float mean = S * (1.f / 128.f);
    float var = Q * (1.f / 128.f) - mean * mean;
    float b1v = 0.f;
    if (t < 128) {
        b1v = (t1 - mean) / sqrtf(var + 1e-5f) * n1g[t] + n1b[t];
        b1row[t] = b1v;
    }
    __syncthreads();
    ff1[t] = gelu_exact(fb1[t] + dot128_4(b1row, fw1 + t * DMm));
    __syncthreads();
    ps[seg][o] = dot128_4(ff1 + seg * 128, fw2 + o * 512 + seg * 128);
    __syncthreads();
    float t2 = 0.f;
    if (t < 128) t2 = b1v + fb2[t] + ((ps[0][t] + ps[1][t]) + (ps[2][t] + ps[3][t]));
    sa = (t < 128) ? t2 : 0.f; sb = (t < 128) ? t2 * t2 : 0.f;
#pragma unroll
    for (int off = 1; off < 64; off <<= 1) { sa += __shfl_xor(sa, off); sb += __shfl_xor(sb, off); }
    if ((t & 63) == 0) { redC[t >> 6] = sa; redD[t >> 6] = sb; }
    __syncthreads();
    S = 0.f; Q = 0.f;
#pragma unroll
    for (int r = 0; r < 8; ++r) { S += redC[r]; Q += redD[r]; }
    mean = S * (1.f / 128.f);
    var = Q * (1.f / 128.f) - mean * mean;
    if (t < 128) {
        float nv = (t2 - mean) / sqrtf(var + 1e-5f) * n2g[t] + n2b[t];
        bnd[bc * DMm + t] = nv;
        bndrow[t] = nv;
    }
    if (!do_qkv) return;
    __syncthreads();
    if (t < 384) {
        const int which = t >> 7;
        const float* W  = (which == 0) ? qw : (which == 1) ? kw : vw;
        const float* Bi = (which == 0) ? qb : (which == 1) ? kb : vb;
        float val = Bi[o] + dot128_4(bndrow, W + o * DMm);
        const int h = o >> 5, dd = o & 31;
        const int gi = ((b * Hh + h) * Cc + c) * DHh + dd;
        if (which == 0)      { q[gi] = val; qrow[o] = val; }
        else if (which == 1) { k[gi] = val; krow[o] = val; }
        else                 { v[gi] = val; }
    }
    __syncthreads();
    if (t < 128) {
        const int h = t >> 5, dd = t & 31;
        const float* wrq = w1 + dd * 96;
        float aq = 0.f, ak = 0.f;
#pragma unroll
        for (int e = 0; e < DHh; ++e) {
            aq = fmaf(qrow[h * 32 + e], wrq[e],      aq);
            ak = fmaf(krow[h * 32 + e], wrq[32 + e], ak);
        }
        const int gi = ((b * Hh + h) * Cc + c) * DHh + dd;
        qp[gi] = aq; kp[gi] = ak;
    }
}

// ---------------- K6+K7 fused: slots GRU (s<64) and task-query readout (s==64) -------------
__global__ __launch_bounds__(256) void k_slots(const float* __restrict__ bnd,
                                               const float* __restrict__ slots,
                                               const float* __restrict__ tq,
                                               const float* __restrict__ wih,
                                               const float* __restrict__ whh,
                                               const float* __restrict__ bih,
                                               const float* __restrict__ bhh,
                                               float* __restrict__ contrib,
                                               float* __restrict__ hbuf) {
    __shared__ float sl[DMm], a2[Cc], ctx2[2][128], ctxs[DMm], giS[3 * DMm], ghS[3 * DMm];
    __shared__ float redM[4], redS[4];
    const int bid = blockIdx.x;
    const int b = bid / 65, s = bid % 65;
    const int t = threadIdx.x;
    if (t < DMm) sl[t] = (s < Ss) ? slots[s * DMm + t] : tq[t];
    __syncthreads();
    float sv = dot128_4(sl, bnd + (b * Cc + t) * DMm) * 0.08838834764831845f;
    float m = sv;
#pragma unroll
    for (int off = 1; off < 64; off <<= 1) m = fmaxf(m, __shfl_xor(m, off));
    if ((t & 63) == 0) redM[t >> 6] = m;
    __syncthreads();
    float mxv = fmaxf(fmaxf(redM[0], redM[1]), fmaxf(redM[2], redM[3]));
    float ev = expf(sv - mxv);
    float su = ev;
#pragma unroll
    for (int off = 1; off < 64; off <<= 1) su += __shfl_xor(su, off);
    if ((t & 63) == 0) redS[t >> 6] = su;
    __syncthreads();
    float sum = (redS[0] + redS[1]) + (redS[2] + redS[3]);
    a2[t] = ev / sum;
    __syncthreads();
    {
        const int o = t & 127, seg = t >> 7;
        float cacc = 0.f;
        for (int cc = 0; cc < 128; ++cc) {
            int c = seg * 128 + cc;
            cacc = fmaf(a2[c], bnd[(b * Cc + c) * DMm + o], cacc);
        }
        ctx2[seg][o] = cacc;
    }
    __syncthreads();
    if (t < DMm) ctxs[t] = ctx2[0][t] + ctx2[1][t];
    __syncthreads();
    if (s == Ss) {
        if (t < DMm) hbuf[b * DMm + t] = ctxs[t];
        return;
    }
    giS[t] = bih[t] + dot128_4(ctxs, wih + t * DMm);
    ghS[t] = bhh[t] + dot128_4(sl, whh + t * DMm);
    if (t < DMm) {
        int o = 256 + t;
        giS[o] = bih[o] + dot128_4(ctxs, wih + o * DMm);
        ghS[o] = bhh[o] + dot128_4(sl, whh + o * DMm);
    }
    __syncthreads();
    if (t < DMm) {
        float r = 1.f / (1.f + expf(-(giS[t] + ghS[t])));
        float z = 1.f / (1.f + expf(-(giS[128 + t] + ghS[128 + t])));
        float n = tanhf(giS[256 + t] + r * ghS[256 + t]);
        contrib[(b * Ss + s) * DMm + t] = (1.f - z) * n + z * sl[t];
    }
}

// ---------------- K8: mem LN + head ----------------
__global__ __launch_bounds__(128) void k_final(const float* __restrict__ contrib,
                                               const float* __restrict__ hbuf,
                                               const float* __restrict__ mg, const float* __restrict__ mb,
                                               const float* __restrict__ hw, const float* __restrict__ hb,
                                               float* __restrict__ out) {
    __shared__ float hm[DMm], redA[2], redB[2];
    const int b = blockIdx.x, t = threadIdx.x;
    float acc = 0.f;
    for (int s = 0; s < Ss; ++s) acc += contrib[(b * Ss + s) * DMm + t];
    acc *= (1.f / (float)Ss);
    float sa = acc, sb = acc * acc;
#pragma unroll
    for (int off = 1; off < 64; off <<= 1) { sa += __shfl_xor(sa, off); sb += __shfl_xor(sb, off); }
    if ((t & 63) == 0) { redA[t >> 6] = sa; redB[t >> 6] = sb; }
    __syncthreads();
    float S = redA[0] + redA[1], Q = redB[0] + redB[1];
    float mean = S * (1.f / 128.f);
    float var = Q * (1.f / 128.f) - mean * mean;
    float memv = (acc - mean) / sqrtf(var + 1e-5f) * mg[t] + mb[t];
    hm[t] = hbuf[b * DMm + t] + memv;
    __syncthreads();
    if (t < OUTn) {
        float o = hb[t];
        const float* wr = hw + t * DMm;
#pragma unroll 16
        for (int e = 0; e < DMm; ++e) o = fmaf(hm[e], wr[e], o);
        out[b * OUTn + t] = o;
    }
}

extern "C" void kernel_launch(void* const* d_in, const int* in_sizes, int n_in,
                              void* d_out, int out_size, void* d_ws, size_t ws_size,
                              hipStream_t stream) {
    const float* x         = (const float*)d_in[0];
    const float* emb_roles = (const float*)d_in[1];
    const float* filler_w  = (const float*)d_in[2];
    const float* conv_w    = (const float*)d_in[3];
    const float* conv_b    = (const float*)d_in[4];
    const float* outer_w   = (const float*)d_in[5];
    const float* enc_ng    = (const float*)d_in[6];
    const float* enc_nb    = (const float*)d_in[7];
    const float* qw        = (const float*)d_in[8];
    const float* qb        = (const float*)d_in[9];
    const float* kw        = (const float*)d_in[10];
    const float* kb        = (const float*)d_in[11];
    const float* vw        = (const float*)d_in[12];
    const float* vb        = (const float*)d_in[13];
    const float* rel_w1    = (const float*)d_in[14];
    const float* rel_b1    = (const float*)d_in[15];
    const float* rel_w2    = (const float*)d_in[16];
    const float* rel_b2    = (const float*)d_in[17];
    const float* ow        = (const float*)d_in[18];
    const float* ob        = (const float*)d_in[19];
    const float* n1g       = (const float*)d_in[20];
    const float* n1b       = (const float*)d_in[21];
    const float* n2g       = (const float*)d_in[22];
    const float* n2b       = (const float*)d_in[23];
    const float* ffn_w1    = (const float*)d_in[24];
    const float* ffn_b1    = (const float*)d_in[25];
    const float* ffn_w2    = (const float*)d_in[26];
    const float* ffn_b2    = (const float*)d_in[27];
    const float* task_q    = (const float*)d_in[28];
    const float* slots     = (const float*)d_in[29];
    const float* gru_wih   = (const float*)d_in[30];
    const float* gru_whh   = (const float*)d_in[31];
    const float* gru_bih   = (const float*)d_in[32];
    const float* gru_bhh   = (const float*)d_in[33];
    const float* mem_ng    = (const float*)d_in[34];
    const float* mem_nb    = (const float*)d_in[35];
    const float* head_w    = (const float*)d_in[36];
    const float* head_b    = (const float*)d_in[37];

    float* ws = (float*)d_ws;
    const int BC = Bb * Cc;                 // 512
    const int BHCD = Bb * Hh * Cc * DHh;    // 65536
    float* valsb = ws;                      // 512
    float* mzb   = valsb + BC;              // 512
    float* bnd   = mzb + BC;                // 65536
    float* qB    = bnd + BC * DMm;
    float* kB    = qB + BHCD;
    float* vB    = kB + BHCD;
    float* qpB   = vB + BHCD;
    float* kpB   = qpB + BHCD;
    float* aout  = kpB + BHCD;              // 65536
    float* hbuf  = aout + BC * DMm;         // 256
    float* contrib = hbuf + Bb * DMm;       // 16384

    k_topk<<<Bb, 1024, 0, stream>>>(x, valsb, mzb);
    k_enc_qkv<<<BC, 256, 0, stream>>>(valsb, mzb, emb_roles, filler_w, conv_w, conv_b,
                                      outer_w, enc_ng, enc_nb, bnd,
                                      qw, qb, kw, kb, vw, vb, rel_w1,
                                      qB, kB, vB, qpB, kpB);
    for (int l = 0; l < Ll; ++l) {
        k_attn<<<Bb * 2 * Cc, 256, 0, stream>>>(qB, kB, vB, qpB, kpB,
                                                rel_w1 + l * DHh * 3 * DHh,
                                                rel_b1 + l * DHh,
                                                rel_w2 + l * DHh,
                                                rel_b2 + l,
                                                aout);
        int nl = l + 1;
        int do_qkv = (nl < Ll) ? 1 : 0;
        int wl = do_qkv ? nl : 0;
        k_ffn_qkv<<<BC, 512, 0, stream>>>(aout,
                                          ow + l * DMm * DMm, ob + l * DMm,
                                          n1g + l * DMm, n1b + l * DMm,
                                          ffn_w1 + l * 4 * DMm * DMm, ffn_b1 + l * 4 * DMm,
                                          ffn_w2 + l * 4 * DMm * DMm, ffn_b2 + l * DMm,
                                          n2g + l * DMm, n2b + l * DMm,
                                          bnd, do_qkv,
                                          qw + wl * DMm * DMm, qb + wl * DMm,
                                          kw + wl * DMm * DMm, kb + wl * DMm,
                                          vw + wl * DMm * DMm, vb + wl * DMm,
                                          rel_w1 + wl * DHh * 3 * DHh,
                                          qB, kB, vB, qpB, kpB);
    }
    k_slots<<<Bb * (Ss + 1), 256, 0, stream>>>(bnd, slots, task_q, gru_wih, gru_whh,
                                               gru_bih, gru_bhh, contrib, hbuf);
    k_final<<<Bb, 128, 0, stream>>>(contrib, hbuf, mem_ng, mem_nb, head_w, head_b, (float*)d_out);
}